// Round 1
// baseline (1436.905 us; speedup 1.0000x reference)
//
#include <hip/hip_runtime.h>

#define NN 100000
#define EE 3200000
#define NCHUNKS 391   // ceil(NN/256)

// workspace layout (bytes), all 256-aligned
#define OFF_A    0UL            // float[NN*64]  25,600,000
#define OFF_B    25600000UL     // float[NN*64]  25,600,000
#define OFF_CSR  51200000UL     // int[EE]       12,800,000
#define OFF_DEG  64000000UL     // int[NN]          400,384 (padded)
#define OFF_DINV 64400384UL     // float[NN]        400,384
#define OFF_RP   64800768UL     // int[NN+1]        401,408
#define OFF_CUR  65202176UL     // int[NN]          400,384
#define OFF_PART 65602560UL     // int[512]           4,096
#define OFF_BN   65606656UL     // float[128]         1,024
#define OFF_SS   65607680UL     // float[128]         1,024
// total ~65.6 MB

__global__ __launch_bounds__(256) void deg_count(const int* __restrict__ dst, int* __restrict__ deg) {
    for (int i = blockIdx.x * blockDim.x + threadIdx.x; i < EE; i += gridDim.x * blockDim.x)
        atomicAdd(&deg[dst[i]], 1);
}

__global__ __launch_bounds__(256) void dinv_k(const int* __restrict__ deg, float* __restrict__ dinv) {
    int i = blockIdx.x * 256 + threadIdx.x;
    if (i < NN) dinv[i] = rsqrtf((float)deg[i] + 1.0f);
}

__global__ __launch_bounds__(256) void chunk_sums(const int* __restrict__ deg, int* __restrict__ part) {
    __shared__ int s[256];
    int t = threadIdx.x, i = blockIdx.x * 256 + t;
    s[t] = (i < NN) ? deg[i] : 0;
    __syncthreads();
    for (int off = 128; off; off >>= 1) {
        if (t < off) s[t] += s[t + off];
        __syncthreads();
    }
    if (t == 0) part[blockIdx.x] = s[0];
}

__global__ __launch_bounds__(512) void scan_partials(int* __restrict__ part) {
    __shared__ int s[512];
    int t = threadIdx.x;
    int v = (t < NCHUNKS) ? part[t] : 0;
    s[t] = v;
    __syncthreads();
    for (int off = 1; off < 512; off <<= 1) {
        int xv = (t >= off) ? s[t - off] : 0;
        __syncthreads();
        s[t] += xv;
        __syncthreads();
    }
    if (t < NCHUNKS) part[t] = s[t] - v;   // exclusive prefix of chunk sums
}

__global__ __launch_bounds__(256) void scan_chunks(const int* __restrict__ deg, const int* __restrict__ part,
                                                   int* __restrict__ rp, int* __restrict__ cur) {
    __shared__ int s[256];
    int t = threadIdx.x, i = blockIdx.x * 256 + t;
    int v = (i < NN) ? deg[i] : 0;
    s[t] = v;
    __syncthreads();
    for (int off = 1; off < 256; off <<= 1) {
        int xv = (t >= off) ? s[t - off] : 0;
        __syncthreads();
        s[t] += xv;
        __syncthreads();
    }
    if (i < NN) {
        int ex = part[blockIdx.x] + s[t] - v;   // exclusive global prefix
        rp[i] = ex;
        cur[i] = ex;
        if (i == NN - 1) rp[NN] = ex + v;       // == EE
    }
}

__global__ __launch_bounds__(256) void csr_fill(const int* __restrict__ src, const int* __restrict__ dst,
                                                int* __restrict__ cur, int* __restrict__ csr) {
    for (int i = blockIdx.x * blockDim.x + threadIdx.x; i < EE; i += gridDim.x * blockDim.x) {
        int p = atomicAdd(&cur[dst[i]], 1);
        csr[p] = src[i];
    }
}

// A[N,64] = x[N,256] @ W1[256,64]
__global__ __launch_bounds__(256) void gemm1(const float* __restrict__ x, const float* __restrict__ W1,
                                             float* __restrict__ A) {
    __shared__ float w1s[256 * 64];
    for (int i = threadIdx.x; i < 4096; i += 256)
        ((float4*)w1s)[i] = ((const float4*)W1)[i];
    __syncthreads();
    int wid = threadIdx.x >> 6, lane = threadIdx.x & 63;
    const int ngroups = NN / 4;   // 4 rows per wave
    for (int g = blockIdx.x * 4 + wid; g < ngroups; g += gridDim.x * 4) {
        const float* xr = x + (size_t)g * 1024;
        float a0 = 0.f, a1 = 0.f, a2 = 0.f, a3 = 0.f;
        for (int k4 = 0; k4 < 64; ++k4) {
            float4 x0 = *(const float4*)(xr + k4 * 4);
            float4 x1 = *(const float4*)(xr + 256 + k4 * 4);
            float4 x2 = *(const float4*)(xr + 512 + k4 * 4);
            float4 x3 = *(const float4*)(xr + 768 + k4 * 4);
            const float* wr = &w1s[k4 * 256 + lane];
            float w0 = wr[0], w1v = wr[64], w2v = wr[128], w3v = wr[192];
            a0 += x0.x * w0 + x0.y * w1v + x0.z * w2v + x0.w * w3v;
            a1 += x1.x * w0 + x1.y * w1v + x1.z * w2v + x1.w * w3v;
            a2 += x2.x * w0 + x2.y * w1v + x2.z * w2v + x2.w * w3v;
            a3 += x3.x * w0 + x3.y * w1v + x3.z * w2v + x3.w * w3v;
        }
        float* Ar = A + (size_t)g * 256 + lane;
        Ar[0] = a0; Ar[64] = a1; Ar[128] = a2; Ar[192] = a3;
    }
}

// out[d,:] = dinv[d]^2 * h[d,:] + dinv[d] * sum_{s in in(d)} dinv[s] * h[s,:]   (64 ch, wave per node)
__global__ __launch_bounds__(256) void agg64(const float* __restrict__ h, float* __restrict__ out,
                                             const int* __restrict__ rp, const int* __restrict__ csr,
                                             const float* __restrict__ dinv) {
    int lane = threadIdx.x & 63;
    int node = (blockIdx.x << 2) + (threadIdx.x >> 6);
    if (node >= NN) return;
    float dd = dinv[node];
    float hself = h[(size_t)node * 64 + lane];
    float accE = 0.f;
    int beg = rp[node], end = rp[node + 1];
    for (int j0 = beg; j0 < end; j0 += 64) {
        int rem = end - j0;
        int m = rem < 64 ? rem : 64;
        int s = csr[j0 + (lane < rem ? lane : 0)];
        float dv = dinv[s];
        for (int j = 0; j < m; ++j) {
            int sj = __shfl(s, j);
            float w = __shfl(dv, j);
            accE += w * h[(size_t)sj * 64 + lane];
        }
    }
    out[(size_t)node * 64 + lane] = dd * accE + dd * dd * hself;
}

// same on 32 channels (half-wave per node)
__global__ __launch_bounds__(256) void agg32(const float* __restrict__ h, float* __restrict__ out,
                                             const int* __restrict__ rp, const int* __restrict__ csr,
                                             const float* __restrict__ dinv) {
    int lane = threadIdx.x & 31;
    int node = (blockIdx.x << 3) + (threadIdx.x >> 5);
    if (node >= NN) return;
    float dd = dinv[node];
    float hself = h[(size_t)node * 32 + lane];
    float accE = 0.f;
    int beg = rp[node], end = rp[node + 1];
    for (int j0 = beg; j0 < end; j0 += 32) {
        int rem = end - j0;
        int m = rem < 32 ? rem : 32;
        int s = csr[j0 + (lane < rem ? lane : 0)];
        float dv = dinv[s];
        for (int j = 0; j < m; ++j) {
            int sj = __shfl(s, j, 32);
            float w = __shfl(dv, j, 32);
            accE += w * h[(size_t)sj * 32 + lane];
        }
    }
    out[(size_t)node * 32 + lane] = dd * accE + dd * dd * hself;
}

__global__ __launch_bounds__(256) void bn_stats(const float* __restrict__ A, float* __restrict__ bn) {
    int t = threadIdx.x;
    int c = t & 63, rg = t >> 6;
    float s = 0.f, sq = 0.f;
    for (int r = blockIdx.x * 4 + rg; r < NN; r += gridDim.x * 4) {
        float v = A[(size_t)r * 64 + c];
        s += v; sq += v * v;
    }
    __shared__ float ls[256], lq[256];
    ls[t] = s; lq[t] = sq;
    __syncthreads();
    if (t < 64) {
        float S = ls[t] + ls[t + 64] + ls[t + 128] + ls[t + 192];
        float Q = lq[t] + lq[t + 64] + lq[t + 128] + lq[t + 192];
        atomicAdd(&bn[t], S);
        atomicAdd(&bn[64 + t], Q);
    }
}

__global__ void bn_final(const float* __restrict__ bn, const float* __restrict__ gamma,
                         const float* __restrict__ beta, float* __restrict__ ss) {
    int c = threadIdx.x;   // 64 threads
    float mean = bn[c] / (float)NN;
    float var = bn[64 + c] / (float)NN - mean * mean;
    float sc = gamma[c] * rsqrtf(var + 1e-5f);
    ss[c] = sc;
    ss[64 + c] = beta[c] - mean * sc;
}

// U[N,32] = selu(bn(A[N,64])) @ W2[64,32]   (BN+SELU fused into the read)
__global__ __launch_bounds__(256) void gemm2(const float* __restrict__ A, const float* __restrict__ W2,
                                             const float* __restrict__ ss, float* __restrict__ U) {
    __shared__ float w2s[64 * 32];
    __shared__ float sc[64], sh[64];
    for (int i = threadIdx.x; i < 512; i += 256)
        ((float4*)w2s)[i] = ((const float4*)W2)[i];
    if (threadIdx.x < 64) {
        sc[threadIdx.x] = ss[threadIdx.x];
        sh[threadIdx.x] = ss[64 + threadIdx.x];
    }
    __syncthreads();
    const float SELU_S = 1.0507009873554805f;
    const float SELU_AS = 1.7580993408473766f;   // scale*alpha
    int lane = threadIdx.x & 31, grp = threadIdx.x >> 5;
    for (int node = blockIdx.x * 8 + grp; node < NN; node += gridDim.x * 8) {
        const float4* zr = (const float4*)(A + (size_t)node * 64);
        float acc = 0.f;
        for (int k4 = 0; k4 < 16; ++k4) {
            float4 z4 = zr[k4];
            #pragma unroll
            for (int j = 0; j < 4; ++j) {
                int k = k4 * 4 + j;
                float v = (&z4.x)[j] * sc[k] + sh[k];
                v = v > 0.f ? SELU_S * v : SELU_AS * (expf(v) - 1.0f);
                acc += v * w2s[k * 32 + lane];
            }
        }
        U[(size_t)node * 32 + lane] = acc;
    }
}

__global__ __launch_bounds__(256) void logsm(const float* __restrict__ C, const float* __restrict__ b2,
                                             float* __restrict__ outp) {
    int lane = threadIdx.x & 31, grp = threadIdx.x >> 5;
    int node = blockIdx.x * 8 + grp;
    if (node >= NN) return;
    float v = C[(size_t)node * 32 + lane] + b2[lane];
    float m = v;
    for (int off = 16; off; off >>= 1) m = fmaxf(m, __shfl_xor(m, off, 32));
    float ex = expf(v - m);
    float s1 = ex;
    for (int off = 16; off; off >>= 1) s1 += __shfl_xor(s1, off, 32);
    outp[(size_t)node * 32 + lane] = v - m - logf(s1);
}

extern "C" void kernel_launch(void* const* d_in, const int* in_sizes, int n_in,
                              void* d_out, int out_size, void* d_ws, size_t ws_size,
                              hipStream_t stream) {
    const float* x     = (const float*)d_in[0];
    const int*   src   = (const int*)d_in[1];
    const int*   dst   = (const int*)d_in[2];
    const float* W1    = (const float*)d_in[3];
    // d_in[4] = b1 : cancels inside BatchNorm, unused
    const float* gamma = (const float*)d_in[5];
    const float* beta  = (const float*)d_in[6];
    const float* W2    = (const float*)d_in[7];
    const float* b2    = (const float*)d_in[8];
    float* out = (float*)d_out;

    char* ws = (char*)d_ws;
    float* A    = (float*)(ws + OFF_A);
    float* B    = (float*)(ws + OFF_B);
    int*   csr  = (int*)(ws + OFF_CSR);
    int*   deg  = (int*)(ws + OFF_DEG);
    float* dinv = (float*)(ws + OFF_DINV);
    int*   rp   = (int*)(ws + OFF_RP);
    int*   cur  = (int*)(ws + OFF_CUR);
    int*   part = (int*)(ws + OFF_PART);
    float* bn   = (float*)(ws + OFF_BN);
    float* ssb  = (float*)(ws + OFF_SS);

    hipMemsetAsync(deg, 0, NN * sizeof(int), stream);
    hipMemsetAsync(bn, 0, 128 * sizeof(float), stream);

    // graph normalization + CSR build (per launch, deterministic work)
    deg_count<<<2048, 256, 0, stream>>>(dst, deg);
    dinv_k<<<NCHUNKS, 256, 0, stream>>>(deg, dinv);
    chunk_sums<<<NCHUNKS, 256, 0, stream>>>(deg, part);
    scan_partials<<<1, 512, 0, stream>>>(part);
    scan_chunks<<<NCHUNKS, 256, 0, stream>>>(deg, part, rp, cur);
    csr_fill<<<2048, 256, 0, stream>>>(src, dst, cur, csr);

    // conv1: A = x@W1, then two propagations (on 64 dims, not 256)
    gemm1<<<512, 256, 0, stream>>>(x, W1, A);
    agg64<<<NN / 4, 256, 0, stream>>>(A, B, rp, csr, dinv);
    agg64<<<NN / 4, 256, 0, stream>>>(B, A, rp, csr, dinv);

    // batchnorm stats (b1 cancels), fold gamma/beta into scale/shift
    bn_stats<<<1024, 256, 0, stream>>>(A, bn);
    bn_final<<<1, 64, 0, stream>>>(bn, gamma, beta, ssb);

    // conv2: U = selu(bn(A)) @ W2 (fused), then propagate on 32 dims
    gemm2<<<NN / 8, 256, 0, stream>>>(A, W2, ssb, B);
    agg32<<<NN / 8, 256, 0, stream>>>(B, A, rp, csr, dinv);

    // + b2 and row log_softmax
    logsm<<<NN / 8, 256, 0, stream>>>(A, b2, out);
}

// Round 2
// 1188.807 us; speedup vs baseline: 1.2087x; 1.2087x over previous
//
#include <hip/hip_runtime.h>

#define NN 100000
#define EE 3200000
#define NCHUNKS 391   // ceil(NN/256)

// workspace layout (bytes), all 256-aligned
#define OFF_A    0UL            // float[NN*64]  25,600,000
#define OFF_B    25600000UL     // float[NN*64]  25,600,000
#define OFF_CSR  51200000UL     // int[EE]       12,800,000
#define OFF_DEG  64000000UL     // int[NN]          400,384 (padded)
#define OFF_DINV 64400384UL     // float[NN]        400,384
#define OFF_RP   64800768UL     // int[NN+1]        401,408
#define OFF_CUR  65202176UL     // int[NN]          400,384
#define OFF_PART 65602560UL     // int[512]           4,096
#define OFF_BN   65606656UL     // float[128]         1,024
#define OFF_SS   65607680UL     // float[128]         1,024
// total ~65.6 MB

__global__ __launch_bounds__(256) void deg_count(const int* __restrict__ dst, int* __restrict__ deg) {
    for (int i = blockIdx.x * blockDim.x + threadIdx.x; i < EE; i += gridDim.x * blockDim.x)
        atomicAdd(&deg[dst[i]], 1);
}

__global__ __launch_bounds__(256) void dinv_k(const int* __restrict__ deg, float* __restrict__ dinv) {
    int i = blockIdx.x * 256 + threadIdx.x;
    if (i < NN) dinv[i] = rsqrtf((float)deg[i] + 1.0f);
}

__global__ __launch_bounds__(256) void chunk_sums(const int* __restrict__ deg, int* __restrict__ part) {
    __shared__ int s[256];
    int t = threadIdx.x, i = blockIdx.x * 256 + t;
    s[t] = (i < NN) ? deg[i] : 0;
    __syncthreads();
    for (int off = 128; off; off >>= 1) {
        if (t < off) s[t] += s[t + off];
        __syncthreads();
    }
    if (t == 0) part[blockIdx.x] = s[0];
}

__global__ __launch_bounds__(512) void scan_partials(int* __restrict__ part) {
    __shared__ int s[512];
    int t = threadIdx.x;
    int v = (t < NCHUNKS) ? part[t] : 0;
    s[t] = v;
    __syncthreads();
    for (int off = 1; off < 512; off <<= 1) {
        int xv = (t >= off) ? s[t - off] : 0;
        __syncthreads();
        s[t] += xv;
        __syncthreads();
    }
    if (t < NCHUNKS) part[t] = s[t] - v;   // exclusive prefix of chunk sums
}

__global__ __launch_bounds__(256) void scan_chunks(const int* __restrict__ deg, const int* __restrict__ part,
                                                   int* __restrict__ rp, int* __restrict__ cur) {
    __shared__ int s[256];
    int t = threadIdx.x, i = blockIdx.x * 256 + t;
    int v = (i < NN) ? deg[i] : 0;
    s[t] = v;
    __syncthreads();
    for (int off = 1; off < 256; off <<= 1) {
        int xv = (t >= off) ? s[t - off] : 0;
        __syncthreads();
        s[t] += xv;
        __syncthreads();
    }
    if (i < NN) {
        int ex = part[blockIdx.x] + s[t] - v;   // exclusive global prefix
        rp[i] = ex;
        cur[i] = ex;
        if (i == NN - 1) rp[NN] = ex + v;       // == EE
    }
}

__global__ __launch_bounds__(256) void csr_fill(const int* __restrict__ src, const int* __restrict__ dst,
                                                int* __restrict__ cur, int* __restrict__ csr) {
    for (int i = blockIdx.x * blockDim.x + threadIdx.x; i < EE; i += gridDim.x * blockDim.x) {
        int p = atomicAdd(&cur[dst[i]], 1);
        csr[p] = src[i];
    }
}

// A'[N,64] = dinv[i] * (x[N,256] @ W1[256,64])   (pre-scaled for the first aggregation)
__global__ __launch_bounds__(256) void gemm1(const float* __restrict__ x, const float* __restrict__ W1,
                                             const float* __restrict__ dinv, float* __restrict__ A) {
    __shared__ float w1s[256 * 64];
    for (int i = threadIdx.x; i < 4096; i += 256)
        ((float4*)w1s)[i] = ((const float4*)W1)[i];
    __syncthreads();
    int wid = threadIdx.x >> 6, lane = threadIdx.x & 63;
    const int ngroups = NN / 4;   // 4 rows per wave
    for (int g = blockIdx.x * 4 + wid; g < ngroups; g += gridDim.x * 4) {
        const float* xr = x + (size_t)g * 1024;
        float a0 = 0.f, a1 = 0.f, a2 = 0.f, a3 = 0.f;
        for (int k4 = 0; k4 < 64; ++k4) {
            float4 x0 = *(const float4*)(xr + k4 * 4);
            float4 x1 = *(const float4*)(xr + 256 + k4 * 4);
            float4 x2 = *(const float4*)(xr + 512 + k4 * 4);
            float4 x3 = *(const float4*)(xr + 768 + k4 * 4);
            const float* wr = &w1s[k4 * 256 + lane];
            float w0 = wr[0], w1v = wr[64], w2v = wr[128], w3v = wr[192];
            a0 += x0.x * w0 + x0.y * w1v + x0.z * w2v + x0.w * w3v;
            a1 += x1.x * w0 + x1.y * w1v + x1.z * w2v + x1.w * w3v;
            a2 += x2.x * w0 + x2.y * w1v + x2.z * w2v + x2.w * w3v;
            a3 += x3.x * w0 + x3.y * w1v + x3.z * w2v + x3.w * w3v;
        }
        float* Ar = A + (size_t)g * 256 + lane;
        Ar[0]   = a0 * dinv[g * 4];
        Ar[64]  = a1 * dinv[g * 4 + 1];
        Ar[128] = a2 * dinv[g * 4 + 2];
        Ar[192] = a3 * dinv[g * 4 + 3];
    }
}

// Input g[i] = dinv[i]*h[i] (pre-scaled). out[d] = dinv[d]^P * (g[d] + sum_{s in in(d)} g[s])
// P=2 -> output stays pre-scaled for a following aggregation; P=1 -> true values.
template <int P>
__global__ __launch_bounds__(256) void agg64(const float* __restrict__ h, float* __restrict__ out,
                                             const int* __restrict__ rp, const int* __restrict__ csr,
                                             const float* __restrict__ dinv) {
    int lane = threadIdx.x & 63;
    int node = (blockIdx.x << 2) + (threadIdx.x >> 6);
    if (node >= NN) return;
    float dd = dinv[node];
    float acc = h[(size_t)node * 64 + lane];   // self term (already pre-scaled)
    int beg = rp[node], end = rp[node + 1];
    for (int j0 = beg; j0 < end; j0 += 64) {
        int rem = end - j0;
        int m = rem < 64 ? rem : 64;
        int s = csr[j0 + (lane < rem ? lane : 0)];
        for (int j = 0; j < m; ++j) {
            int sj = __shfl(s, j);
            acc += h[(size_t)sj * 64 + lane];
        }
    }
    float w = (P == 2) ? dd * dd : dd;
    out[(size_t)node * 64 + lane] = w * acc;
}

// 32-channel aggregation, input pre-scaled, output true values (P=1)
__global__ __launch_bounds__(256) void agg32(const float* __restrict__ h, float* __restrict__ out,
                                             const int* __restrict__ rp, const int* __restrict__ csr,
                                             const float* __restrict__ dinv) {
    int lane = threadIdx.x & 31;
    int node = (blockIdx.x << 3) + (threadIdx.x >> 5);
    if (node >= NN) return;
    float dd = dinv[node];
    float acc = h[(size_t)node * 32 + lane];
    int beg = rp[node], end = rp[node + 1];
    for (int j0 = beg; j0 < end; j0 += 32) {
        int rem = end - j0;
        int m = rem < 32 ? rem : 32;
        int s = csr[j0 + (lane < rem ? lane : 0)];
        for (int j = 0; j < m; ++j) {
            int sj = __shfl(s, j, 32);
            acc += h[(size_t)sj * 32 + lane];
        }
    }
    out[(size_t)node * 32 + lane] = dd * acc;
}

__global__ __launch_bounds__(256) void bn_stats(const float* __restrict__ A, float* __restrict__ bn) {
    int t = threadIdx.x;
    int c = t & 63, rg = t >> 6;
    float s = 0.f, sq = 0.f;
    for (int r = blockIdx.x * 4 + rg; r < NN; r += gridDim.x * 4) {
        float v = A[(size_t)r * 64 + c];
        s += v; sq += v * v;
    }
    __shared__ float ls[256], lq[256];
    ls[t] = s; lq[t] = sq;
    __syncthreads();
    if (t < 64) {
        float S = ls[t] + ls[t + 64] + ls[t + 128] + ls[t + 192];
        float Q = lq[t] + lq[t + 64] + lq[t + 128] + lq[t + 192];
        atomicAdd(&bn[t], S);
        atomicAdd(&bn[64 + t], Q);
    }
}

__global__ void bn_final(const float* __restrict__ bn, const float* __restrict__ gamma,
                         const float* __restrict__ beta, float* __restrict__ ss) {
    int c = threadIdx.x;   // 64 threads
    float mean = bn[c] / (float)NN;
    float var = bn[64 + c] / (float)NN - mean * mean;
    float sc = gamma[c] * rsqrtf(var + 1e-5f);
    ss[c] = sc;
    ss[64 + c] = beta[c] - mean * sc;
}

// U'[N,32] = dinv[i] * (selu(bn(A[N,64])) @ W2[64,32])   (BN+SELU fused, output pre-scaled)
__global__ __launch_bounds__(256) void gemm2(const float* __restrict__ A, const float* __restrict__ W2,
                                             const float* __restrict__ ss, const float* __restrict__ dinv,
                                             float* __restrict__ U) {
    __shared__ float w2s[64 * 32];
    __shared__ float sc[64], sh[64];
    for (int i = threadIdx.x; i < 512; i += 256)
        ((float4*)w2s)[i] = ((const float4*)W2)[i];
    if (threadIdx.x < 64) {
        sc[threadIdx.x] = ss[threadIdx.x];
        sh[threadIdx.x] = ss[64 + threadIdx.x];
    }
    __syncthreads();
    const float SELU_S = 1.0507009873554805f;
    const float SELU_AS = 1.7580993408473766f;   // scale*alpha
    int lane = threadIdx.x & 31, grp = threadIdx.x >> 5;
    int node = blockIdx.x * 8 + grp;
    if (node >= NN) return;
    const float* Ar = A + (size_t)node * 64;
    float v0 = Ar[lane];
    float v1 = Ar[lane + 32];
    v0 = v0 * sc[lane] + sh[lane];
    v1 = v1 * sc[lane + 32] + sh[lane + 32];
    v0 = v0 > 0.f ? SELU_S * v0 : SELU_AS * (__expf(v0) - 1.0f);
    v1 = v1 > 0.f ? SELU_S * v1 : SELU_AS * (__expf(v1) - 1.0f);
    float acc = 0.f;
    #pragma unroll
    for (int j = 0; j < 32; ++j) {
        acc += __shfl(v0, j, 32) * w2s[j * 32 + lane];
        acc += __shfl(v1, j, 32) * w2s[(j + 32) * 32 + lane];
    }
    U[(size_t)node * 32 + lane] = dinv[node] * acc;
}

__global__ __launch_bounds__(256) void logsm(const float* __restrict__ C, const float* __restrict__ b2,
                                             float* __restrict__ outp) {
    int lane = threadIdx.x & 31, grp = threadIdx.x >> 5;
    int node = blockIdx.x * 8 + grp;
    if (node >= NN) return;
    float v = C[(size_t)node * 32 + lane] + b2[lane];
    float m = v;
    for (int off = 16; off; off >>= 1) m = fmaxf(m, __shfl_xor(m, off, 32));
    float ex = expf(v - m);
    float s1 = ex;
    for (int off = 16; off; off >>= 1) s1 += __shfl_xor(s1, off, 32);
    outp[(size_t)node * 32 + lane] = v - m - logf(s1);
}

extern "C" void kernel_launch(void* const* d_in, const int* in_sizes, int n_in,
                              void* d_out, int out_size, void* d_ws, size_t ws_size,
                              hipStream_t stream) {
    const float* x     = (const float*)d_in[0];
    const int*   src   = (const int*)d_in[1];
    const int*   dst   = (const int*)d_in[2];
    const float* W1    = (const float*)d_in[3];
    // d_in[4] = b1 : cancels inside BatchNorm, unused
    const float* gamma = (const float*)d_in[5];
    const float* beta  = (const float*)d_in[6];
    const float* W2    = (const float*)d_in[7];
    const float* b2    = (const float*)d_in[8];
    float* out = (float*)d_out;

    char* ws = (char*)d_ws;
    float* A    = (float*)(ws + OFF_A);
    float* B    = (float*)(ws + OFF_B);
    int*   csr  = (int*)(ws + OFF_CSR);
    int*   deg  = (int*)(ws + OFF_DEG);
    float* dinv = (float*)(ws + OFF_DINV);
    int*   rp   = (int*)(ws + OFF_RP);
    int*   cur  = (int*)(ws + OFF_CUR);
    int*   part = (int*)(ws + OFF_PART);
    float* bn   = (float*)(ws + OFF_BN);
    float* ssb  = (float*)(ws + OFF_SS);

    hipMemsetAsync(deg, 0, NN * sizeof(int), stream);
    hipMemsetAsync(bn, 0, 128 * sizeof(float), stream);

    // graph normalization + CSR build (per launch, deterministic work)
    deg_count<<<2048, 256, 0, stream>>>(dst, deg);
    dinv_k<<<NCHUNKS, 256, 0, stream>>>(deg, dinv);
    chunk_sums<<<NCHUNKS, 256, 0, stream>>>(deg, part);
    scan_partials<<<1, 512, 0, stream>>>(part);
    scan_chunks<<<NCHUNKS, 256, 0, stream>>>(deg, part, rp, cur);
    csr_fill<<<2048, 256, 0, stream>>>(src, dst, cur, csr);

    // conv1: A' = dinv*(x@W1), then two propagations (on 64 dims, not 256)
    gemm1<<<512, 256, 0, stream>>>(x, W1, dinv, A);
    agg64<2><<<NN / 4, 256, 0, stream>>>(A, B, rp, csr, dinv);   // B stays pre-scaled
    agg64<1><<<NN / 4, 256, 0, stream>>>(B, A, rp, csr, dinv);   // A = true h2

    // batchnorm stats (b1 cancels), fold gamma/beta into scale/shift
    bn_stats<<<1024, 256, 0, stream>>>(A, bn);
    bn_final<<<1, 64, 0, stream>>>(bn, gamma, beta, ssb);

    // conv2: U' = dinv * (selu(bn(A)) @ W2) (fused), then propagate on 32 dims
    gemm2<<<NN / 8, 256, 0, stream>>>(A, W2, ssb, dinv, B);
    agg32<<<NN / 8, 256, 0, stream>>>(B, A, rp, csr, dinv);

    // + b2 and row log_softmax
    logsm<<<NN / 8, 256, 0, stream>>>(A, b2, out);
}

// Round 3
// 1165.468 us; speedup vs baseline: 1.2329x; 1.0200x over previous
//
#include <hip/hip_runtime.h>

#define NN 100000
#define EE 3200000
#define NB 256          // dst-range buckets
#define NPB 391         // nodes per bucket = ceil(NN/NB)
#define NCLS 8          // XCD classes (blockIdx & 7)
#define CAP 2048        // per (class,bucket) capacity (mean 1562, +12 sigma)
#define EBUF_CAP 13568  // per-bucket total capacity (mean 12500, +9.5 sigma)

// workspace layout (bytes)
#define OFF_A    0UL            // float[NN*64] 25.6MB  (bucket_buf 16.8MB overlays this pre-gemm1)
#define OFF_B    25600000UL     // float[NN*64] 25.6MB
#define OFF_CSR  51200000UL     // int[EE]      12.8MB
#define OFF_RP   64000000UL     // int[NN+1]
#define OFF_DINV 64400384UL     // float[NN]
#define OFF_SEG  64800768UL     // int[2048]
#define OFF_BASE 64808960UL     // int[257]
#define OFF_BN   64813056UL     // float[128]
#define OFF_SS   64813568UL     // float[128]
// total ~64.8 MB

// ---- CSR build: bucket radix scatter ----
__global__ __launch_bounds__(256) void passA(const int* __restrict__ src, const int* __restrict__ dst,
                                             int* __restrict__ segcnt, unsigned* __restrict__ buf) {
    int c = blockIdx.x & (NCLS - 1);
    for (int i = blockIdx.x * 256 + threadIdx.x; i < EE; i += gridDim.x * 256) {
        int d = dst[i];
        int b = d / NPB;            // compile-time magic-mul
        int dl = d - b * NPB;
        int slot = c * NB + b;
        int p = atomicAdd(&segcnt[slot], 1);
        if (p < CAP)
            buf[(size_t)slot * CAP + p] = ((unsigned)dl << 17) | (unsigned)src[i];
    }
}

__global__ __launch_bounds__(256) void scan_buckets(const int* __restrict__ segcnt,
                                                    int* __restrict__ base, int* __restrict__ rp) {
    __shared__ int s[256];
    int t = threadIdx.x;
    int tot = 0;
    for (int c = 0; c < NCLS; ++c) tot += segcnt[c * NB + t];
    s[t] = tot;
    __syncthreads();
    for (int off = 1; off < 256; off <<= 1) {
        int v = (t >= off) ? s[t - off] : 0;
        __syncthreads();
        s[t] += v;
        __syncthreads();
    }
    base[t] = s[t] - tot;           // exclusive
    if (t == 255) { base[256] = s[255]; rp[NN] = s[255]; }
}

// per-bucket: stage entries in LDS, count deg, scan, emit rp/dinv, scatter csr
__global__ __launch_bounds__(256) void passB(const unsigned* __restrict__ buf,
                                             const int* __restrict__ segcnt,
                                             const int* __restrict__ base,
                                             int* __restrict__ rp, float* __restrict__ dinv,
                                             int* __restrict__ csr) {
    __shared__ unsigned ebuf[EBUF_CAP];
    __shared__ int deg_l[NPB];
    __shared__ int off_l[NPB];
    __shared__ int s[256];
    __shared__ int segoff[NCLS + 1];
    __shared__ int tot0;
    int b = blockIdx.x, t = threadIdx.x;
    if (t == 0) {
        int o = 0;
        for (int c = 0; c < NCLS; ++c) { segoff[c] = o; o += min(segcnt[c * NB + b], CAP); }
        segoff[NCLS] = o;
    }
    for (int i = t; i < NPB; i += 256) deg_l[i] = 0;
    __syncthreads();
    int nb = segoff[NCLS];
    for (int c = 0; c < NCLS; ++c) {
        int o = segoff[c], n = segoff[c + 1] - o;
        const unsigned* sp = buf + (size_t)(c * NB + b) * CAP;
        for (int j = t; j < n; j += 256) ebuf[o + j] = sp[j];
    }
    __syncthreads();
    for (int j = t; j < nb; j += 256) atomicAdd(&deg_l[ebuf[j] >> 17], 1);
    __syncthreads();
    // exclusive scan deg_l[0..NPB) -> off_l : chunk [0,256) then [256,391)
    int d0 = deg_l[t];
    s[t] = d0;
    __syncthreads();
    for (int off = 1; off < 256; off <<= 1) {
        int v = (t >= off) ? s[t - off] : 0;
        __syncthreads();
        s[t] += v;
        __syncthreads();
    }
    off_l[t] = s[t] - d0;
    if (t == 255) tot0 = s[255];
    __syncthreads();
    int i1 = 256 + t;
    int d1 = (i1 < NPB) ? deg_l[i1] : 0;
    s[t] = d1;
    __syncthreads();
    for (int off = 1; off < 256; off <<= 1) {
        int v = (t >= off) ? s[t - off] : 0;
        __syncthreads();
        s[t] += v;
        __syncthreads();
    }
    if (i1 < NPB) off_l[i1] = tot0 + s[t] - d1;
    __syncthreads();
    int nodebase = b * NPB;
    int cbase = base[b];
    for (int i = t; i < NPB; i += 256) {
        int node = nodebase + i;
        if (node < NN) {
            rp[node] = cbase + off_l[i];
            dinv[node] = rsqrtf((float)deg_l[i] + 1.0f);
        }
    }
    __syncthreads();
    // scatter using off_l as LDS cursors
    for (int j = t; j < nb; j += 256) {
        unsigned e = ebuf[j];
        int p = atomicAdd(&off_l[e >> 17], 1);
        csr[cbase + p] = (int)(e & 0x1FFFFu);
    }
}

// A'[N,64] = dinv[i] * (x[N,256] @ W1[256,64])   (pre-scaled for the first aggregation)
__global__ __launch_bounds__(256) void gemm1(const float* __restrict__ x, const float* __restrict__ W1,
                                             const float* __restrict__ dinv, float* __restrict__ A) {
    __shared__ float w1s[256 * 64];
    for (int i = threadIdx.x; i < 4096; i += 256)
        ((float4*)w1s)[i] = ((const float4*)W1)[i];
    __syncthreads();
    int wid = threadIdx.x >> 6, lane = threadIdx.x & 63;
    const int ngroups = NN / 4;   // 4 rows per wave
    for (int g = blockIdx.x * 4 + wid; g < ngroups; g += gridDim.x * 4) {
        const float* xr = x + (size_t)g * 1024;
        float a0 = 0.f, a1 = 0.f, a2 = 0.f, a3 = 0.f;
        for (int k4 = 0; k4 < 64; ++k4) {
            float4 x0 = *(const float4*)(xr + k4 * 4);
            float4 x1 = *(const float4*)(xr + 256 + k4 * 4);
            float4 x2 = *(const float4*)(xr + 512 + k4 * 4);
            float4 x3 = *(const float4*)(xr + 768 + k4 * 4);
            const float* wr = &w1s[k4 * 256 + lane];
            float w0 = wr[0], w1v = wr[64], w2v = wr[128], w3v = wr[192];
            a0 += x0.x * w0 + x0.y * w1v + x0.z * w2v + x0.w * w3v;
            a1 += x1.x * w0 + x1.y * w1v + x1.z * w2v + x1.w * w3v;
            a2 += x2.x * w0 + x2.y * w1v + x2.z * w2v + x2.w * w3v;
            a3 += x3.x * w0 + x3.y * w1v + x3.z * w2v + x3.w * w3v;
        }
        float* Ar = A + (size_t)g * 256 + lane;
        Ar[0]   = a0 * dinv[g * 4];
        Ar[64]  = a1 * dinv[g * 4 + 1];
        Ar[128] = a2 * dinv[g * 4 + 2];
        Ar[192] = a3 * dinv[g * 4 + 3];
    }
}

// Input g[i] = dinv[i]*h[i] (pre-scaled). out[d] = dinv[d]^P * (g[d] + sum_{s in in(d)} g[s])
template <int P>
__global__ __launch_bounds__(256) void agg64(const float* __restrict__ h, float* __restrict__ out,
                                             const int* __restrict__ rp, const int* __restrict__ csr,
                                             const float* __restrict__ dinv) {
    int lane = threadIdx.x & 63;
    int node = (blockIdx.x << 2) + (threadIdx.x >> 6);
    if (node >= NN) return;
    float dd = dinv[node];
    float acc = h[(size_t)node * 64 + lane];   // self term (pre-scaled)
    int beg = rp[node], end = rp[node + 1];
    for (int j0 = beg; j0 < end; j0 += 64) {
        int rem = end - j0;
        int m = rem < 64 ? rem : 64;
        int s = csr[j0 + (lane < rem ? lane : 0)];
        for (int j = 0; j < m; ++j) {
            int sj = __shfl(s, j);
            acc += h[(size_t)sj * 64 + lane];
        }
    }
    float w = (P == 2) ? dd * dd : dd;
    out[(size_t)node * 64 + lane] = w * acc;
}

// 32-channel aggregation, input pre-scaled, output true values
__global__ __launch_bounds__(256) void agg32(const float* __restrict__ h, float* __restrict__ out,
                                             const int* __restrict__ rp, const int* __restrict__ csr,
                                             const float* __restrict__ dinv) {
    int lane = threadIdx.x & 31;
    int node = (blockIdx.x << 3) + (threadIdx.x >> 5);
    if (node >= NN) return;
    float dd = dinv[node];
    float acc = h[(size_t)node * 32 + lane];
    int beg = rp[node], end = rp[node + 1];
    for (int j0 = beg; j0 < end; j0 += 32) {
        int rem = end - j0;
        int m = rem < 32 ? rem : 32;
        int s = csr[j0 + (lane < rem ? lane : 0)];
        for (int j = 0; j < m; ++j) {
            int sj = __shfl(s, j, 32);
            acc += h[(size_t)sj * 32 + lane];
        }
    }
    out[(size_t)node * 32 + lane] = dd * acc;
}

__global__ __launch_bounds__(256) void bn_stats(const float* __restrict__ A, float* __restrict__ bn) {
    int t = threadIdx.x;
    int c = t & 63, rg = t >> 6;
    float s = 0.f, sq = 0.f;
    for (int r = blockIdx.x * 4 + rg; r < NN; r += gridDim.x * 4) {
        float v = A[(size_t)r * 64 + c];
        s += v; sq += v * v;
    }
    __shared__ float ls[256], lq[256];
    ls[t] = s; lq[t] = sq;
    __syncthreads();
    if (t < 64) {
        float S = ls[t] + ls[t + 64] + ls[t + 128] + ls[t + 192];
        float Q = lq[t] + lq[t + 64] + lq[t + 128] + lq[t + 192];
        atomicAdd(&bn[t], S);
        atomicAdd(&bn[64 + t], Q);
    }
}

__global__ void bn_final(const float* __restrict__ bn, const float* __restrict__ gamma,
                         const float* __restrict__ beta, float* __restrict__ ss) {
    int c = threadIdx.x;   // 64 threads
    float mean = bn[c] / (float)NN;
    float var = bn[64 + c] / (float)NN - mean * mean;
    float sc = gamma[c] * rsqrtf(var + 1e-5f);
    ss[c] = sc;
    ss[64 + c] = beta[c] - mean * sc;
}

// U'[N,32] = dinv[i] * (selu(bn(A[N,64])) @ W2[64,32])
__global__ __launch_bounds__(256) void gemm2(const float* __restrict__ A, const float* __restrict__ W2,
                                             const float* __restrict__ ss, const float* __restrict__ dinv,
                                             float* __restrict__ U) {
    __shared__ float w2s[64 * 32];
    __shared__ float sc[64], sh[64];
    for (int i = threadIdx.x; i < 512; i += 256)
        ((float4*)w2s)[i] = ((const float4*)W2)[i];
    if (threadIdx.x < 64) {
        sc[threadIdx.x] = ss[threadIdx.x];
        sh[threadIdx.x] = ss[64 + threadIdx.x];
    }
    __syncthreads();
    const float SELU_S = 1.0507009873554805f;
    const float SELU_AS = 1.7580993408473766f;   // scale*alpha
    int lane = threadIdx.x & 31, grp = threadIdx.x >> 5;
    int node = blockIdx.x * 8 + grp;
    if (node >= NN) return;
    const float* Ar = A + (size_t)node * 64;
    float v0 = Ar[lane];
    float v1 = Ar[lane + 32];
    v0 = v0 * sc[lane] + sh[lane];
    v1 = v1 * sc[lane + 32] + sh[lane + 32];
    v0 = v0 > 0.f ? SELU_S * v0 : SELU_AS * (__expf(v0) - 1.0f);
    v1 = v1 > 0.f ? SELU_S * v1 : SELU_AS * (__expf(v1) - 1.0f);
    float acc = 0.f;
    #pragma unroll
    for (int j = 0; j < 32; ++j) {
        acc += __shfl(v0, j, 32) * w2s[j * 32 + lane];
        acc += __shfl(v1, j, 32) * w2s[(j + 32) * 32 + lane];
    }
    U[(size_t)node * 32 + lane] = dinv[node] * acc;
}

__global__ __launch_bounds__(256) void logsm(const float* __restrict__ C, const float* __restrict__ b2,
                                             float* __restrict__ outp) {
    int lane = threadIdx.x & 31, grp = threadIdx.x >> 5;
    int node = blockIdx.x * 8 + grp;
    if (node >= NN) return;
    float v = C[(size_t)node * 32 + lane] + b2[lane];
    float m = v;
    for (int off = 16; off; off >>= 1) m = fmaxf(m, __shfl_xor(m, off, 32));
    float ex = expf(v - m);
    float s1 = ex;
    for (int off = 16; off; off >>= 1) s1 += __shfl_xor(s1, off, 32);
    outp[(size_t)node * 32 + lane] = v - m - logf(s1);
}

extern "C" void kernel_launch(void* const* d_in, const int* in_sizes, int n_in,
                              void* d_out, int out_size, void* d_ws, size_t ws_size,
                              hipStream_t stream) {
    const float* x     = (const float*)d_in[0];
    const int*   src   = (const int*)d_in[1];
    const int*   dst   = (const int*)d_in[2];
    const float* W1    = (const float*)d_in[3];
    // d_in[4] = b1 : cancels inside BatchNorm, unused
    const float* gamma = (const float*)d_in[5];
    const float* beta  = (const float*)d_in[6];
    const float* W2    = (const float*)d_in[7];
    const float* b2    = (const float*)d_in[8];
    float* out = (float*)d_out;

    char* ws = (char*)d_ws;
    float*    A    = (float*)(ws + OFF_A);
    unsigned* bbuf = (unsigned*)(ws + OFF_A);   // overlays A pre-gemm1
    float*    B    = (float*)(ws + OFF_B);
    int*      csr  = (int*)(ws + OFF_CSR);
    int*      rp   = (int*)(ws + OFF_RP);
    float*    dinv = (float*)(ws + OFF_DINV);
    int*      seg  = (int*)(ws + OFF_SEG);
    int*      base = (int*)(ws + OFF_BASE);
    float*    bn   = (float*)(ws + OFF_BN);
    float*    ssb  = (float*)(ws + OFF_SS);

    hipMemsetAsync(seg, 0, NCLS * NB * sizeof(int), stream);
    hipMemsetAsync(bn, 0, 128 * sizeof(float), stream);

    // CSR build: bucket radix (also produces rp + dinv)
    passA<<<2048, 256, 0, stream>>>(src, dst, seg, bbuf);
    scan_buckets<<<1, 256, 0, stream>>>(seg, base, rp);
    passB<<<NB, 256, 0, stream>>>(bbuf, seg, base, rp, dinv, csr);

    // conv1: A' = dinv*(x@W1), then two propagations (on 64 dims, not 256)
    gemm1<<<512, 256, 0, stream>>>(x, W1, dinv, A);
    agg64<2><<<NN / 4, 256, 0, stream>>>(A, B, rp, csr, dinv);   // B stays pre-scaled
    agg64<1><<<NN / 4, 256, 0, stream>>>(B, A, rp, csr, dinv);   // A = true h2

    // batchnorm stats (b1 cancels), fold gamma/beta into scale/shift
    bn_stats<<<1024, 256, 0, stream>>>(A, bn);
    bn_final<<<1, 64, 0, stream>>>(bn, gamma, beta, ssb);

    // conv2: U' = dinv*(selu(bn(A)) @ W2) (fused), then propagate on 32 dims
    gemm2<<<NN / 8, 256, 0, stream>>>(A, W2, ssb, dinv, B);
    agg32<<<NN / 8, 256, 0, stream>>>(B, A, rp, csr, dinv);

    // + b2 and row log_softmax
    logsm<<<NN / 8, 256, 0, stream>>>(A, b2, out);
}

// Round 4
// 663.099 us; speedup vs baseline: 2.1670x; 1.7576x over previous
//
#include <hip/hip_runtime.h>

#define NN 100000
#define EE 3200000
#define NB 256          // dst-range buckets
#define NPB 391         // nodes per bucket = ceil(NN/NB)
#define BCAP 13568      // per-bucket buffer capacity (mean 12500, +9.5 sigma)
#define NBLK_A 256      // passA blocks
#define CHUNK_A (EE / NBLK_A)   // 12500 edges per block

// workspace layout (bytes)
#define OFF_A    0UL            // float[NN*64] 25.6MB  (bucket_buf 13.9MB overlays this pre-gemm1)
#define OFF_B    25600000UL     // float[NN*64] 25.6MB
#define OFF_CSR  51200000UL     // int[EE]      12.8MB
#define OFF_RP   64000000UL     // int[NN+1]
#define OFF_DINV 64400384UL     // float[NN]
#define OFF_SEG  64800768UL     // int[256]
#define OFF_BASE 64808960UL     // int[257]
#define OFF_BN   64813056UL     // float[128]
#define OFF_SS   64813568UL     // float[128]
// total ~64.8 MB

// ---- CSR build: privatized-histogram bucket scatter ----
// Each block: LDS histogram of its 12500-edge chunk -> 1 global atomic per bucket
// to reserve a contiguous run -> LDS-cursor scatter (mostly full-line writes).
__global__ __launch_bounds__(256) void passA(const int* __restrict__ src, const int* __restrict__ dst,
                                             int* __restrict__ segcnt, unsigned* __restrict__ buf) {
    __shared__ int hist[NB];
    __shared__ int curl[NB];
    int t = threadIdx.x;
    hist[t] = 0;
    __syncthreads();
    int beg = blockIdx.x * CHUNK_A, end = beg + CHUNK_A;
    for (int i = beg + t; i < end; i += 256)
        atomicAdd(&hist[dst[i] / NPB], 1);
    __syncthreads();
    int h = hist[t];
    int r = atomicAdd(&segcnt[t], h);
    curl[t] = t * BCAP + r;
    __syncthreads();
    for (int i = beg + t; i < end; i += 256) {
        int d = dst[i];
        int k = d / NPB;
        int dl = d - k * NPB;
        int p = atomicAdd(&curl[k], 1);
        if (p < (k + 1) * BCAP)   // safety clamp (~9 sigma, never in practice)
            buf[p] = ((unsigned)dl << 17) | (unsigned)src[i];
    }
}

__global__ __launch_bounds__(256) void scan_buckets(const int* __restrict__ segcnt,
                                                    int* __restrict__ base, int* __restrict__ rp) {
    __shared__ int s[256];
    int t = threadIdx.x;
    int tot = min(segcnt[t], BCAP);
    s[t] = tot;
    __syncthreads();
    for (int off = 1; off < 256; off <<= 1) {
        int v = (t >= off) ? s[t - off] : 0;
        __syncthreads();
        s[t] += v;
        __syncthreads();
    }
    base[t] = s[t] - tot;           // exclusive
    if (t == 255) { base[256] = s[255]; rp[NN] = s[255]; }
}

// per-bucket: stage entries in LDS, count deg, scan, emit rp/dinv, scatter csr
__global__ __launch_bounds__(256) void passB(const unsigned* __restrict__ buf,
                                             const int* __restrict__ segcnt,
                                             const int* __restrict__ base,
                                             int* __restrict__ rp, float* __restrict__ dinv,
                                             int* __restrict__ csr) {
    __shared__ unsigned ebuf[BCAP];
    __shared__ int deg_l[NPB];
    __shared__ int off_l[NPB];
    __shared__ int s[256];
    __shared__ int tot0;
    int b = blockIdx.x, t = threadIdx.x;
    int nb = min(segcnt[b], BCAP);
    for (int i = t; i < NPB; i += 256) deg_l[i] = 0;
    const unsigned* sp = buf + (size_t)b * BCAP;
    for (int j = t; j < nb; j += 256) ebuf[j] = sp[j];
    __syncthreads();
    for (int j = t; j < nb; j += 256) atomicAdd(&deg_l[ebuf[j] >> 17], 1);
    __syncthreads();
    // exclusive scan deg_l[0..NPB) -> off_l : chunk [0,256) then [256,391)
    int d0 = deg_l[t];
    s[t] = d0;
    __syncthreads();
    for (int off = 1; off < 256; off <<= 1) {
        int v = (t >= off) ? s[t - off] : 0;
        __syncthreads();
        s[t] += v;
        __syncthreads();
    }
    off_l[t] = s[t] - d0;
    if (t == 255) tot0 = s[255];
    __syncthreads();
    int i1 = 256 + t;
    int d1 = (i1 < NPB) ? deg_l[i1] : 0;
    s[t] = d1;
    __syncthreads();
    for (int off = 1; off < 256; off <<= 1) {
        int v = (t >= off) ? s[t - off] : 0;
        __syncthreads();
        s[t] += v;
        __syncthreads();
    }
    if (i1 < NPB) off_l[i1] = tot0 + s[t] - d1;
    __syncthreads();
    int nodebase = b * NPB;
    int cbase = base[b];
    for (int i = t; i < NPB; i += 256) {
        int node = nodebase + i;
        if (node < NN) {
            rp[node] = cbase + off_l[i];
            dinv[node] = rsqrtf((float)deg_l[i] + 1.0f);
        }
    }
    __syncthreads();
    // scatter using off_l as LDS cursors
    for (int j = t; j < nb; j += 256) {
        unsigned e = ebuf[j];
        int p = atomicAdd(&off_l[e >> 17], 1);
        csr[cbase + p] = (int)(e & 0x1FFFFu);
    }
}

// A'[N,64] = dinv[i] * (x[N,256] @ W1[256,64])   (pre-scaled for the first aggregation)
__global__ __launch_bounds__(256) void gemm1(const float* __restrict__ x, const float* __restrict__ W1,
                                             const float* __restrict__ dinv, float* __restrict__ A) {
    __shared__ float w1s[256 * 64];
    for (int i = threadIdx.x; i < 4096; i += 256)
        ((float4*)w1s)[i] = ((const float4*)W1)[i];
    __syncthreads();
    int wid = threadIdx.x >> 6, lane = threadIdx.x & 63;
    const int ngroups = NN / 4;   // 4 rows per wave
    for (int g = blockIdx.x * 4 + wid; g < ngroups; g += gridDim.x * 4) {
        const float* xr = x + (size_t)g * 1024;
        float a0 = 0.f, a1 = 0.f, a2 = 0.f, a3 = 0.f;
        for (int k4 = 0; k4 < 64; ++k4) {
            float4 x0 = *(const float4*)(xr + k4 * 4);
            float4 x1 = *(const float4*)(xr + 256 + k4 * 4);
            float4 x2 = *(const float4*)(xr + 512 + k4 * 4);
            float4 x3 = *(const float4*)(xr + 768 + k4 * 4);
            const float* wr = &w1s[k4 * 256 + lane];
            float w0 = wr[0], w1v = wr[64], w2v = wr[128], w3v = wr[192];
            a0 += x0.x * w0 + x0.y * w1v + x0.z * w2v + x0.w * w3v;
            a1 += x1.x * w0 + x1.y * w1v + x1.z * w2v + x1.w * w3v;
            a2 += x2.x * w0 + x2.y * w1v + x2.z * w2v + x2.w * w3v;
            a3 += x3.x * w0 + x3.y * w1v + x3.z * w2v + x3.w * w3v;
        }
        float* Ar = A + (size_t)g * 256 + lane;
        Ar[0]   = a0 * dinv[g * 4];
        Ar[64]  = a1 * dinv[g * 4 + 1];
        Ar[128] = a2 * dinv[g * 4 + 2];
        Ar[192] = a3 * dinv[g * 4 + 3];
    }
}

// Input g[i] = dinv[i]*h[i] (pre-scaled). out[d] = dinv[d]^P * (g[d] + sum_{s in in(d)} g[s])
// 8x unrolled gather loop: keep 8 row-loads in flight per wave.
template <int P>
__global__ __launch_bounds__(256) void agg64(const float* __restrict__ h, float* __restrict__ out,
                                             const int* __restrict__ rp, const int* __restrict__ csr,
                                             const float* __restrict__ dinv) {
    int lane = threadIdx.x & 63;
    int node = (blockIdx.x << 2) + (threadIdx.x >> 6);
    if (node >= NN) return;
    float dd = dinv[node];
    float a0 = h[(size_t)node * 64 + lane], a1 = 0.f, a2 = 0.f, a3 = 0.f;
    int beg = rp[node], end = rp[node + 1];
    for (int j0 = beg; j0 < end; j0 += 64) {
        int rem = end - j0;
        int m = rem < 64 ? rem : 64;
        int s = csr[j0 + (lane < rem ? lane : 0)];
        int j = 0;
        for (; j + 7 < m; j += 8) {
            int s0 = __shfl(s, j),     s1 = __shfl(s, j + 1);
            int s2 = __shfl(s, j + 2), s3 = __shfl(s, j + 3);
            int s4 = __shfl(s, j + 4), s5 = __shfl(s, j + 5);
            int s6 = __shfl(s, j + 6), s7 = __shfl(s, j + 7);
            float v0 = h[(size_t)s0 * 64 + lane];
            float v1 = h[(size_t)s1 * 64 + lane];
            float v2 = h[(size_t)s2 * 64 + lane];
            float v3 = h[(size_t)s3 * 64 + lane];
            float v4 = h[(size_t)s4 * 64 + lane];
            float v5 = h[(size_t)s5 * 64 + lane];
            float v6 = h[(size_t)s6 * 64 + lane];
            float v7 = h[(size_t)s7 * 64 + lane];
            a0 += v0; a1 += v1; a2 += v2; a3 += v3;
            a0 += v4; a1 += v5; a2 += v6; a3 += v7;
        }
        for (; j < m; ++j)
            a0 += h[(size_t)__shfl(s, j) * 64 + lane];
    }
    float acc = (a0 + a1) + (a2 + a3);
    float w = (P == 2) ? dd * dd : dd;
    out[(size_t)node * 64 + lane] = w * acc;
}

// 32-channel aggregation, input pre-scaled, output true values
__global__ __launch_bounds__(256) void agg32(const float* __restrict__ h, float* __restrict__ out,
                                             const int* __restrict__ rp, const int* __restrict__ csr,
                                             const float* __restrict__ dinv) {
    int lane = threadIdx.x & 31;
    int node = (blockIdx.x << 3) + (threadIdx.x >> 5);
    if (node >= NN) return;
    float dd = dinv[node];
    float a0 = h[(size_t)node * 32 + lane], a1 = 0.f, a2 = 0.f, a3 = 0.f;
    int beg = rp[node], end = rp[node + 1];
    for (int j0 = beg; j0 < end; j0 += 32) {
        int rem = end - j0;
        int m = rem < 32 ? rem : 32;
        int s = csr[j0 + (lane < rem ? lane : 0)];
        int j = 0;
        for (; j + 7 < m; j += 8) {
            int s0 = __shfl(s, j, 32),     s1 = __shfl(s, j + 1, 32);
            int s2 = __shfl(s, j + 2, 32), s3 = __shfl(s, j + 3, 32);
            int s4 = __shfl(s, j + 4, 32), s5 = __shfl(s, j + 5, 32);
            int s6 = __shfl(s, j + 6, 32), s7 = __shfl(s, j + 7, 32);
            float v0 = h[(size_t)s0 * 32 + lane];
            float v1 = h[(size_t)s1 * 32 + lane];
            float v2 = h[(size_t)s2 * 32 + lane];
            float v3 = h[(size_t)s3 * 32 + lane];
            float v4 = h[(size_t)s4 * 32 + lane];
            float v5 = h[(size_t)s5 * 32 + lane];
            float v6 = h[(size_t)s6 * 32 + lane];
            float v7 = h[(size_t)s7 * 32 + lane];
            a0 += v0; a1 += v1; a2 += v2; a3 += v3;
            a0 += v4; a1 += v5; a2 += v6; a3 += v7;
        }
        for (; j < m; ++j)
            a0 += h[(size_t)__shfl(s, j, 32) * 32 + lane];
    }
    float acc = (a0 + a1) + (a2 + a3);
    out[(size_t)node * 32 + lane] = dd * acc;
}

__global__ __launch_bounds__(256) void bn_stats(const float* __restrict__ A, float* __restrict__ bn) {
    int t = threadIdx.x;
    int c = t & 63, rg = t >> 6;
    float s = 0.f, sq = 0.f;
    for (int r = blockIdx.x * 4 + rg; r < NN; r += gridDim.x * 4) {
        float v = A[(size_t)r * 64 + c];
        s += v; sq += v * v;
    }
    __shared__ float ls[256], lq[256];
    ls[t] = s; lq[t] = sq;
    __syncthreads();
    if (t < 64) {
        float S = ls[t] + ls[t + 64] + ls[t + 128] + ls[t + 192];
        float Q = lq[t] + lq[t + 64] + lq[t + 128] + lq[t + 192];
        atomicAdd(&bn[t], S);
        atomicAdd(&bn[64 + t], Q);
    }
}

__global__ void bn_final(const float* __restrict__ bn, const float* __restrict__ gamma,
                         const float* __restrict__ beta, float* __restrict__ ss) {
    int c = threadIdx.x;   // 64 threads
    float mean = bn[c] / (float)NN;
    float var = bn[64 + c] / (float)NN - mean * mean;
    float sc = gamma[c] * rsqrtf(var + 1e-5f);
    ss[c] = sc;
    ss[64 + c] = beta[c] - mean * sc;
}

// U'[N,32] = dinv[i] * (selu(bn(A[N,64])) @ W2[64,32])
__global__ __launch_bounds__(256) void gemm2(const float* __restrict__ A, const float* __restrict__ W2,
                                             const float* __restrict__ ss, const float* __restrict__ dinv,
                                             float* __restrict__ U) {
    __shared__ float w2s[64 * 32];
    __shared__ float sc[64], sh[64];
    for (int i = threadIdx.x; i < 512; i += 256)
        ((float4*)w2s)[i] = ((const float4*)W2)[i];
    if (threadIdx.x < 64) {
        sc[threadIdx.x] = ss[threadIdx.x];
        sh[threadIdx.x] = ss[64 + threadIdx.x];
    }
    __syncthreads();
    const float SELU_S = 1.0507009873554805f;
    const float SELU_AS = 1.7580993408473766f;   // scale*alpha
    int lane = threadIdx.x & 31, grp = threadIdx.x >> 5;
    int node = blockIdx.x * 8 + grp;
    if (node >= NN) return;
    const float* Ar = A + (size_t)node * 64;
    float v0 = Ar[lane];
    float v1 = Ar[lane + 32];
    v0 = v0 * sc[lane] + sh[lane];
    v1 = v1 * sc[lane + 32] + sh[lane + 32];
    v0 = v0 > 0.f ? SELU_S * v0 : SELU_AS * (__expf(v0) - 1.0f);
    v1 = v1 > 0.f ? SELU_S * v1 : SELU_AS * (__expf(v1) - 1.0f);
    float acc = 0.f;
    #pragma unroll
    for (int j = 0; j < 32; ++j) {
        acc += __shfl(v0, j, 32) * w2s[j * 32 + lane];
        acc += __shfl(v1, j, 32) * w2s[(j + 32) * 32 + lane];
    }
    U[(size_t)node * 32 + lane] = dinv[node] * acc;
}

__global__ __launch_bounds__(256) void logsm(const float* __restrict__ C, const float* __restrict__ b2,
                                             float* __restrict__ outp) {
    int lane = threadIdx.x & 31, grp = threadIdx.x >> 5;
    int node = blockIdx.x * 8 + grp;
    if (node >= NN) return;
    float v = C[(size_t)node * 32 + lane] + b2[lane];
    float m = v;
    for (int off = 16; off; off >>= 1) m = fmaxf(m, __shfl_xor(m, off, 32));
    float ex = expf(v - m);
    float s1 = ex;
    for (int off = 16; off; off >>= 1) s1 += __shfl_xor(s1, off, 32);
    outp[(size_t)node * 32 + lane] = v - m - logf(s1);
}

extern "C" void kernel_launch(void* const* d_in, const int* in_sizes, int n_in,
                              void* d_out, int out_size, void* d_ws, size_t ws_size,
                              hipStream_t stream) {
    const float* x     = (const float*)d_in[0];
    const int*   src   = (const int*)d_in[1];
    const int*   dst   = (const int*)d_in[2];
    const float* W1    = (const float*)d_in[3];
    // d_in[4] = b1 : cancels inside BatchNorm, unused
    const float* gamma = (const float*)d_in[5];
    const float* beta  = (const float*)d_in[6];
    const float* W2    = (const float*)d_in[7];
    const float* b2    = (const float*)d_in[8];
    float* out = (float*)d_out;

    char* ws = (char*)d_ws;
    float*    A    = (float*)(ws + OFF_A);
    unsigned* bbuf = (unsigned*)(ws + OFF_A);   // 13.9MB overlays A pre-gemm1
    float*    B    = (float*)(ws + OFF_B);
    int*      csr  = (int*)(ws + OFF_CSR);
    int*      rp   = (int*)(ws + OFF_RP);
    float*    dinv = (float*)(ws + OFF_DINV);
    int*      seg  = (int*)(ws + OFF_SEG);
    int*      base = (int*)(ws + OFF_BASE);
    float*    bn   = (float*)(ws + OFF_BN);
    float*    ssb  = (float*)(ws + OFF_SS);

    hipMemsetAsync(seg, 0, NB * sizeof(int), stream);
    hipMemsetAsync(bn, 0, 128 * sizeof(float), stream);

    // CSR build: privatized-histogram bucket radix (also produces rp + dinv)
    passA<<<NBLK_A, 256, 0, stream>>>(src, dst, seg, bbuf);
    scan_buckets<<<1, 256, 0, stream>>>(seg, base, rp);
    passB<<<NB, 256, 0, stream>>>(bbuf, seg, base, rp, dinv, csr);

    // conv1: A' = dinv*(x@W1), then two propagations (on 64 dims, not 256)
    gemm1<<<512, 256, 0, stream>>>(x, W1, dinv, A);
    agg64<2><<<NN / 4, 256, 0, stream>>>(A, B, rp, csr, dinv);   // B stays pre-scaled
    agg64<1><<<NN / 4, 256, 0, stream>>>(B, A, rp, csr, dinv);   // A = true h2

    // batchnorm stats (b1 cancels), fold gamma/beta into scale/shift
    bn_stats<<<1024, 256, 0, stream>>>(A, bn);
    bn_final<<<1, 64, 0, stream>>>(bn, gamma, beta, ssb);

    // conv2: U' = dinv*(selu(bn(A)) @ W2) (fused), then propagate on 32 dims
    gemm2<<<NN / 8, 256, 0, stream>>>(A, W2, ssb, dinv, B);
    agg32<<<NN / 8, 256, 0, stream>>>(B, A, rp, csr, dinv);

    // + b2 and row log_softmax
    logsm<<<NN / 8, 256, 0, stream>>>(A, b2, out);
}